// Round 5
// baseline (288.446 us; speedup 1.0000x reference)
//
#include <hip/hip_runtime.h>

#define BATCH 16
#define SEQ   1024
#define DM    512
#define NST   32
#define NC    8           // chunks
#define CL    (SEQ / NC)  // 128
#define NDBLK 8           // d-blocks of 64
#define NBLK  (BATCH * NC * NDBLK)   // 1024 blocks, b in high bits

// E layout: [b][c][ssm][n][d]
#define EIDX(b, c, ssm, n) ((((((size_t)(b) * NC + (c)) * 2 + (ssm)) * NST + (n)) * DM))

__device__ __forceinline__ void group_barrier(unsigned* cnt, unsigned target) {
    __syncthreads();
    if (threadIdx.x == 0) {
        __hip_atomic_fetch_add(cnt, 1u, __ATOMIC_ACQ_REL, __HIP_MEMORY_SCOPE_AGENT);
        while (__hip_atomic_load(cnt, __ATOMIC_ACQUIRE, __HIP_MEMORY_SCOPE_AGENT) < target) {
            __builtin_amdgcn_s_sleep(2);
        }
    }
    __syncthreads();
}

__global__ __launch_bounds__(256, 4) void ssm_fused(
    const float* __restrict__ x,
    const float* __restrict__ Alog_hr, const float* __restrict__ B_hr,
    const float* __restrict__ C_hr,    const float* __restrict__ ldt_hr,
    const float* __restrict__ Alog_br, const float* __restrict__ B_br,
    const float* __restrict__ C_br,    const float* __restrict__ ldt_br,
    const float* __restrict__ w_hr,    const float* __restrict__ w_br,
    float* __restrict__ E, unsigned* __restrict__ flags,
    float* __restrict__ out_hr, float* __restrict__ out_br, float* __restrict__ out_cb)
{
    const int tid  = threadIdx.x;
    const int bid  = blockIdx.x;
    const int b    = bid >> 6;          // high bits -> per-b barrier groups contiguous
    const int c    = (bid >> 3) & (NC - 1);
    const int dblk = bid & (NDBLK - 1);

    // ================= Phase A: local chunk scan, one ssm x 16 states per thread
    {
        const int lane = tid & 63;
        const int wave = tid >> 6;
        const int ssm  = wave & 1;
        const int nh   = wave >> 1;          // n-half: states [nh*16, nh*16+16)
        const int d    = dblk * 64 + lane;

        const float* Alog = ssm ? Alog_br : Alog_hr;
        const float* ldt  = ssm ? ldt_br  : ldt_hr;

        float dt = expf(ldt[d]);
        float dA[16], g[16];
#pragma unroll
        for (int i = 0; i < 16; ++i) {
            dA[i] = expf(dt * expf(Alog[d * NST + nh * 16 + i]));
            g[i]  = 0.f;
        }

        const float* xp = x + ((size_t)b * SEQ + (size_t)c * CL) * DM + d;
#pragma unroll 2
        for (int t = 0; t < CL; ++t) {
            float xv = *xp;  xp += DM;
#pragma unroll
            for (int i = 0; i < 16; ++i) g[i] = fmaf(dA[i], g[i], xv);
        }

        float* ep = E + EIDX(b, c, ssm, nh * 16) + d;
#pragma unroll
        for (int i = 0; i < 16; ++i) ep[(size_t)i * DM] = g[i];
    }

    group_barrier(&flags[b], 64u);

    // ================= Phase B: prefix across chunks; rewrite E in place with INIT states
    {
        const int g  = bid * 256 + tid;      // = b*16384 + ...
        const int d  = g & (DM - 1);
        const int n  = (g >> 9) & (NST - 1);
        // (g >> 14) == b by construction

#pragma unroll
        for (int ssm = 0; ssm < 2; ++ssm) {
            const float* Alog = ssm ? Alog_br : Alog_hr;
            const float* ldt  = ssm ? ldt_br  : ldt_hr;
            float dt = expf(ldt[d]);
            float A  = expf(Alog[d * NST + n]);
            float p  = expf((float)CL * dt * A);   // dA^CL

            float* sp = E + EIDX(b, 0, ssm, n) + d;
            const size_t cstride = (size_t)2 * NST * DM;
            float H = 0.f;
            for (int cc = 0; cc < NC; ++cc) {
                float s = *sp;
                *sp = H;                // init state for chunk cc (H=0 for cc=0)
                H = fmaf(p, H, s);
                sp += cstride;
            }
        }
    }

    group_barrier(&flags[BATCH + b], 64u);

    // ================= Phase C: re-run chunk from init, nq4 n-split, shfl-reduce, emit
    {
        const int lane = tid & 63;
        const int wave = tid >> 6;
        const int nq   = lane >> 4;
        const int dlo  = lane & 15;
        const int d    = dblk * 64 + wave * 16 + dlo;
        const int n0   = nq * 8;

        float dt_h = expf(ldt_hr[d]);
        float dt_b = expf(ldt_br[d]);
        float wh = w_hr[d], wb = w_br[d];

        float dAh[8], dAb[8], Cwh[8], Cwb[8];
#pragma unroll
        for (int i = 0; i < 8; ++i) {
            int n = n0 + i;
            dAh[i] = expf(dt_h * expf(Alog_hr[d * NST + n]));
            dAb[i] = expf(dt_b * expf(Alog_br[d * NST + n]));
            Cwh[i] = C_hr[d * NST + n] * B_hr[d * NST + n] * dt_h * wh;
            Cwb[i] = C_br[d * NST + n] * B_br[d * NST + n] * dt_b * wb;
        }

        float gh[8], gb[8];
        const float* sph = E + EIDX(b, c, 0, n0) + d;
        const float* spb = E + EIDX(b, c, 1, n0) + d;
#pragma unroll
        for (int i = 0; i < 8; ++i) {
            gh[i] = sph[(size_t)i * DM];
            gb[i] = spb[(size_t)i * DM];
        }

        size_t off = ((size_t)b * SEQ + (size_t)c * CL) * DM + d;
        const float* xp = x + off;
        float* op = (nq == 0 ? out_hr : (nq == 1 ? out_br : out_cb)) + off;

#pragma unroll 2
        for (int t = 0; t < CL; ++t) {
            float xv = *xp;  xp += DM;

            float yh0 = 0.f, yh1 = 0.f, yb0 = 0.f, yb1 = 0.f;
#pragma unroll
            for (int i = 0; i < 8; i += 2) {
                gh[i]     = fmaf(dAh[i],     gh[i],     xv);
                gh[i + 1] = fmaf(dAh[i + 1], gh[i + 1], xv);
                gb[i]     = fmaf(dAb[i],     gb[i],     xv);
                gb[i + 1] = fmaf(dAb[i + 1], gb[i + 1], xv);
                yh0 = fmaf(Cwh[i],     gh[i],     yh0);
                yh1 = fmaf(Cwh[i + 1], gh[i + 1], yh1);
                yb0 = fmaf(Cwb[i],     gb[i],     yb0);
                yb1 = fmaf(Cwb[i + 1], gb[i + 1], yb1);
            }
            float yh = yh0 + yh1;
            float yb = yb0 + yb1;

            float th  = __shfl_xor(yh, 16, 64);
            float tb_ = __shfl_xor(yb, 16, 64);
            yh += th;  yb += tb_;
            th  = __shfl_xor(yh, 32, 64);
            tb_ = __shfl_xor(yb, 32, 64);
            yh += th;  yb += tb_;

            float val = (nq == 0) ? yh : ((nq == 1) ? yb : yh + yb);
            *op = val;  op += DM;
        }
    }
}

extern "C" void kernel_launch(void* const* d_in, const int* in_sizes, int n_in,
                              void* d_out, int out_size, void* d_ws, size_t ws_size,
                              hipStream_t stream)
{
    (void)in_sizes; (void)n_in; (void)out_size; (void)ws_size;

    const float* x       = (const float*)d_in[0];
    const float* Alog_hr = (const float*)d_in[1];
    const float* B_hr    = (const float*)d_in[2];
    const float* C_hr    = (const float*)d_in[3];
    const float* ldt_hr  = (const float*)d_in[4];
    const float* Alog_br = (const float*)d_in[5];
    const float* B_br    = (const float*)d_in[6];
    const float* C_br    = (const float*)d_in[7];
    const float* ldt_br  = (const float*)d_in[8];
    const float* w_hr    = (const float*)d_in[9];
    const float* w_br    = (const float*)d_in[10];

    float* out    = (float*)d_out;
    const size_t one = (size_t)BATCH * SEQ * DM;
    float* out_hr = out;
    float* out_br = out + one;
    float* out_cb = out + 2 * one;

    // ws layout: [flags: 32 x u32 (256B pad)] [E: BATCH*NC*2*NST*DM floats = 16.8 MB]
    unsigned* flags = (unsigned*)d_ws;
    float*    E     = (float*)((char*)d_ws + 256);

    hipMemsetAsync(d_ws, 0, 256, stream);
    ssm_fused<<<NBLK, 256, 0, stream>>>(x,
                                        Alog_hr, B_hr, C_hr, ldt_hr,
                                        Alog_br, B_br, C_br, ldt_br,
                                        w_hr, w_br,
                                        E, flags,
                                        out_hr, out_br, out_cb);
}

// Round 6
// 100.282 us; speedup vs baseline: 2.8763x; 2.8763x over previous
//
#include <hip/hip_runtime.h>

#define BATCH 16
#define SEQ   1024
#define DM    512
#define NST   32

// E layout: [ssm][b][c][n][d]

// ---------------- setup: precompute dA and Cw=C*B*dt*w tables, layout [ssm][n][d]
__global__ __launch_bounds__(256) void ssm_setup(
    const float* __restrict__ Alog_hr, const float* __restrict__ B_hr,
    const float* __restrict__ C_hr,    const float* __restrict__ ldt_hr,
    const float* __restrict__ Alog_br, const float* __restrict__ B_br,
    const float* __restrict__ C_br,    const float* __restrict__ ldt_br,
    const float* __restrict__ w_hr,    const float* __restrict__ w_br,
    float* __restrict__ dA_tbl, float* __restrict__ Cw_tbl)
{
    int idx = blockIdx.x * blockDim.x + threadIdx.x;   // (ssm*NST + n)*DM + d
    int d   = idx & (DM - 1);
    int n   = (idx >> 9) & (NST - 1);
    int ssm = idx >> 14;

    const float* Alog = ssm ? Alog_br : Alog_hr;
    const float* Bm   = ssm ? B_br    : B_hr;
    const float* Cm   = ssm ? C_br    : C_hr;
    const float* ldt  = ssm ? ldt_br  : ldt_hr;
    const float* w    = ssm ? w_br    : w_hr;

    float dt = expf(ldt[d]);
    float a  = expf(Alog[d * NST + n]);
    dA_tbl[idx] = expf(dt * a);
    Cw_tbl[idx] = Cm[d * NST + n] * Bm[d * NST + n] * dt * w[d];
}

// ---------------- pass 1: local chunk scans, n-split: one ssm x 16 states per thread
// block covers (ssm,b,c, 128 d) x 2 n-halves; ~40 live floats -> high occupancy
__global__ __launch_bounds__(256) void ssm_pass1(
    const float* __restrict__ x,
    const float* __restrict__ dA_tbl,
    float* __restrict__ ws_state, int nc, int cl)
{
    int tid  = threadIdx.x;
    int dlo  = tid & 127;
    int nh   = tid >> 7;            // n-half
    int bid  = blockIdx.x;          // ((ssm*BATCH+b)*nc + c)*4 + dblk
    int dblk = bid & 3;
    int r    = bid >> 2;
    int c    = r % nc;  r /= nc;
    int b    = r & (BATCH - 1);
    int ssm  = r >> 4;
    int d    = dblk * 128 + dlo;
    int n0   = nh * 16;

    const float* tb = dA_tbl + ((size_t)ssm * NST + n0) * DM + d;
    float dA[16], g[16];
#pragma unroll
    for (int i = 0; i < 16; ++i) {
        dA[i] = tb[(size_t)i * DM];
        g[i]  = 0.f;
    }

    const float* xp = x + ((size_t)b * SEQ + (size_t)c * cl) * DM + d;
#pragma unroll 4
    for (int t = 0; t < cl; ++t) {
        float xv = *xp;  xp += DM;
#pragma unroll
        for (int i = 0; i < 16; ++i) g[i] = fmaf(dA[i], g[i], xv);
    }

    float* sp = ws_state + ((((size_t)ssm * BATCH + b) * nc + c) * NST + n0) * DM + d;
#pragma unroll
    for (int i = 0; i < 16; ++i) sp[(size_t)i * DM] = g[i];
}

// ---------------- pass 2: scan across chunks; rewrite ws with corrected chunk-INITIAL states
__global__ __launch_bounds__(256) void ssm_pass2(
    const float* __restrict__ Alog_hr, const float* __restrict__ ldt_hr,
    const float* __restrict__ Alog_br, const float* __restrict__ ldt_br,
    float* __restrict__ ws_state, int nc, int cl)
{
    int idx = blockIdx.x * blockDim.x + threadIdx.x;   // (((ssm*16+b)*NST+n)*DM + d)
    int d   = idx & (DM - 1);
    int n   = (idx >> 9) & (NST - 1);
    int b   = (idx >> 14) & 15;
    int ssm = idx >> 18;

    const float* Alog = ssm ? Alog_br : Alog_hr;
    const float* ldt  = ssm ? ldt_br  : ldt_hr;

    float dt = expf(ldt[d]);
    float A  = expf(Alog[d * NST + n]);
    float p  = expf((float)cl * dt * A);   // dA^cl

    float* sp = ws_state + ((((size_t)ssm * BATCH + b) * nc) * NST + n) * DM + d;
    size_t cstride = (size_t)NST * DM;

    float H = 0.f;
    for (int c = 0; c < nc; ++c) {
        float s = *sp;
        *sp = H;                 // init state for chunk c
        H = fmaf(p, H, s);       // end state of chunk c
        sp += cstride;
    }
}

// ---------------- pass 3: n-split x4 across lane groups; both ssm; shfl-reduce the dot
// lane = tid&63; nq = lane>>4 owns states [nq*8, nq*8+8); dlo = lane&15.
// nq stores: 0->hr, 1->br, 2->combined, 3->masked off (was a duplicate write)
__global__ __launch_bounds__(256) void ssm_pass3(
    const float* __restrict__ x,
    const float* __restrict__ dA_tbl, const float* __restrict__ Cw_tbl,
    const float* __restrict__ ws_state,
    float* __restrict__ out_hr, float* __restrict__ out_br, float* __restrict__ out_cb,
    int nc, int cl)
{
    int tid  = threadIdx.x;
    int lane = tid & 63;
    int wave = tid >> 6;
    int nq   = lane >> 4;
    int dlo  = lane & 15;
    int bid  = blockIdx.x;          // (b*nc + c)*8 + dblk
    int dblk = bid & 7;
    int r    = bid >> 3;
    int c    = r % nc;
    int b    = r / nc;
    int d    = (dblk << 6) + (wave << 4) + dlo;
    int n0   = nq * 8;

    float dAh[8], dAb[8], Cwh[8], Cwb[8];
#pragma unroll
    for (int i = 0; i < 8; ++i) {
        size_t ih = (size_t)(n0 + i) * DM + d;
        size_t ib = (size_t)(NST + n0 + i) * DM + d;
        dAh[i] = dA_tbl[ih];
        dAb[i] = dA_tbl[ib];
        Cwh[i] = Cw_tbl[ih];
        Cwb[i] = Cw_tbl[ib];
    }

    float gh[8], gb[8];
    if (c == 0) {
#pragma unroll
        for (int i = 0; i < 8; ++i) { gh[i] = 0.f; gb[i] = 0.f; }
    } else {
        const float* sph = ws_state + (((size_t)b * nc + c) * NST + n0) * DM + d;
        const float* spb = sph + (size_t)BATCH * nc * NST * DM;
#pragma unroll
        for (int i = 0; i < 8; ++i) {
            gh[i] = sph[(size_t)i * DM];
            gb[i] = spb[(size_t)i * DM];
        }
    }

    size_t off = ((size_t)b * SEQ + (size_t)c * cl) * DM + d;
    const float* xp = x + off;
    float* op = (nq == 0 ? out_hr : (nq == 1 ? out_br : out_cb)) + off;

#pragma unroll 2
    for (int t = 0; t < cl; ++t) {
        float xv = *xp;  xp += DM;

        float yh0 = 0.f, yh1 = 0.f, yb0 = 0.f, yb1 = 0.f;
#pragma unroll
        for (int i = 0; i < 8; i += 2) {
            gh[i]     = fmaf(dAh[i],     gh[i],     xv);
            gh[i + 1] = fmaf(dAh[i + 1], gh[i + 1], xv);
            gb[i]     = fmaf(dAb[i],     gb[i],     xv);
            gb[i + 1] = fmaf(dAb[i + 1], gb[i + 1], xv);
            yh0 = fmaf(Cwh[i],     gh[i],     yh0);
            yh1 = fmaf(Cwh[i + 1], gh[i + 1], yh1);
            yb0 = fmaf(Cwb[i],     gb[i],     yb0);
            yb1 = fmaf(Cwb[i + 1], gb[i + 1], yb1);
        }
        float yh = yh0 + yh1;
        float yb = yb0 + yb1;

        // reduce over nq (lane bits 4,5)
        float th  = __shfl_xor(yh, 16, 64);
        float tb_ = __shfl_xor(yb, 16, 64);
        yh += th;  yb += tb_;
        th  = __shfl_xor(yh, 32, 64);
        tb_ = __shfl_xor(yb, 32, 64);
        yh += th;  yb += tb_;

        float val = (nq == 0) ? yh : ((nq == 1) ? yb : yh + yb);
        if (nq < 3) *op = val;          // nq=3 would duplicate nq=2's combined write
        op += DM;
    }
}

extern "C" void kernel_launch(void* const* d_in, const int* in_sizes, int n_in,
                              void* d_out, int out_size, void* d_ws, size_t ws_size,
                              hipStream_t stream)
{
    (void)in_sizes; (void)n_in; (void)out_size;

    const float* x       = (const float*)d_in[0];
    const float* Alog_hr = (const float*)d_in[1];
    const float* B_hr    = (const float*)d_in[2];
    const float* C_hr    = (const float*)d_in[3];
    const float* ldt_hr  = (const float*)d_in[4];
    const float* Alog_br = (const float*)d_in[5];
    const float* B_br    = (const float*)d_in[6];
    const float* C_br    = (const float*)d_in[7];
    const float* ldt_br  = (const float*)d_in[8];
    const float* w_hr    = (const float*)d_in[9];
    const float* w_br    = (const float*)d_in[10];

    float* out    = (float*)d_out;
    const size_t one = (size_t)BATCH * SEQ * DM;
    float* out_hr = out;
    float* out_br = out + one;
    float* out_cb = out + 2 * one;

    // ws layout: [dA_tbl 2*NST*DM][Cw_tbl 2*NST*DM][chunk states 2*BATCH*nc*NST*DM]
    float* dA_tbl = (float*)d_ws;
    float* Cw_tbl = dA_tbl + (size_t)2 * NST * DM;
    float* ws_st  = Cw_tbl + (size_t)2 * NST * DM;

    const size_t tbl_bytes = (size_t)4 * NST * DM * sizeof(float);
    int nc = 8;
    while (nc > 1 &&
           ws_size < tbl_bytes + (size_t)2 * BATCH * nc * NST * DM * sizeof(float))
        nc >>= 1;
    int cl = SEQ / nc;

    int total0 = 2 * NST * DM;
    ssm_setup<<<total0 / 256, 256, 0, stream>>>(Alog_hr, B_hr, C_hr, ldt_hr,
                                                Alog_br, B_br, C_br, ldt_br,
                                                w_hr, w_br, dA_tbl, Cw_tbl);

    if (nc > 1) {
        int nblk1 = 2 * BATCH * nc * 4;          // (ssm,b,c) x 4 d-blocks of 128 (x2 nh)
        ssm_pass1<<<nblk1, 256, 0, stream>>>(x, dA_tbl, ws_st, nc, cl);
        int total2 = 2 * BATCH * NST * DM;
        ssm_pass2<<<total2 / 256, 256, 0, stream>>>(Alog_hr, ldt_hr, Alog_br, ldt_br,
                                                    ws_st, nc, cl);
    }

    int nblk3 = BATCH * nc * 8;                  // (b,c) x 8 d-blocks of 64 (x4 nq)
    ssm_pass3<<<nblk3, 256, 0, stream>>>(x, dA_tbl, Cw_tbl, ws_st,
                                         out_hr, out_br, out_cb, nc, cl);
}